// Round 3
// baseline (292.226 us; speedup 1.0000x reference)
//
#include <hip/hip_runtime.h>
#include <hip/hip_cooperative_groups.h>

#define DD 128   // feature dim
#define SR 72    // LDS row stride in bf16 units (64 + 8 pad, bank-spread)
#define PP 128   // partial tiles per matrix
#define NB (2*PP)
#define NT 36    // upper-triangle 16x16 sub-tiles per partial (8*9/2)
#define DOTB 144 // dot-phase blocks = NT*64/16

typedef float f32x4 __attribute__((ext_vector_type(4)));
typedef short s16x8 __attribute__((ext_vector_type(8)));

namespace cg = cooperative_groups;

// ---------------------------------------------------------------------------
// R13: single COOPERATIVE dispatch. R12's three stream-ordered kernels spent
// ~18 us on launch+drain gaps (work itself is ~10 us). Fused:
//   phase 1 (all 256 blocks): per-slab symmetric Gram partials via hi/lo-split
//     bf16 MFMA, 36 upper-triangle 16x16 sub-tiles packed, coalesced dwordx4
//     stores; X-blocks fold diag sums ds1/ds2.
//   grid.sync (+ __threadfence both sides for cross-XCD visibility)
//   phase 2 (blocks 0..143): elementwise sum-over-p then Gx*Gy dot with
//     off-diagonal weight 2 -> prod[blk].
//   grid.sync
//   phase 3 (block 0): reduce 144 prods + 128 ds1/ds2 -> loss.
// Cross-block data flow crosses cg::grid barriers (sanctioned mechanism),
// NOT hand-rolled tickets (R9/R10 failure mode). No atomics.
// ---------------------------------------------------------------------------
__global__ __launch_bounds__(512)
void fused_kernel(const float* __restrict__ x, const float* __restrict__ y,
                  float* __restrict__ apart, float* __restrict__ bpart,
                  double* __restrict__ ds1, double* __restrict__ ds2,
                  double* __restrict__ prod, float* __restrict__ out, int N)
{
  __shared__ __align__(16) unsigned char smem[DD * SR * 2 * sizeof(unsigned short)]; // 36.9 KB
  unsigned short* sh_hi = (unsigned short*)smem;
  unsigned short* sh_lo = sh_hi + DD * SR;
  __shared__ double wred[8][3];

  const int blk = blockIdx.x;
  const int tid = threadIdx.x;
  const int wave = tid >> 6, lane = tid & 63;

  // ================= phase 1: gram partials =================
  {
    const bool isX = blk < PP;
    const int p = isX ? blk : blk - PP;
    const float* __restrict__ src = isX ? x : y;
    const int row0 = p * (N / PP);   // slab = 64 rows

    const int rloc = tid >> 3;     // row within 64-row slab
    const int fg = tid & 7;        // float4 group within row

    // static upper-triangle tile list: wave w owns packed tiles
    // [start, start+cnt), 4 or 5 each.
    const int start = (9 * wave) >> 1;          // {0,4,9,13,18,22,27,31}
    const int cnt = 4 + (wave & 1);             // {4,5,4,5,4,5,4,5}
    int tr_[5], tc_[5];
#pragma unroll
    for (int j = 0; j < 5; ++j) {
      const int tile = start + j;
      int r = 0;
#pragma unroll
      for (int q = 1; q < 8; ++q) r += (tile >= ((q * (17 - q)) >> 1)) ? 1 : 0;
      tr_[j] = r;
      tc_[j] = tile - ((r * (17 - r)) >> 1) + r;
    }

    f32x4 acc[5];
#pragma unroll
    for (int t = 0; t < 5; ++t)
#pragma unroll
      for (int k = 0; k < 4; ++k) acc[t][k] = 0.f;

    double s1 = 0.0, s2 = 0.0;

    const float* cb = src + (size_t)row0 * DD;
    const float4* rowp = (const float4*)(cb + rloc * DD);
    float4 v0 = rowp[fg], v1 = rowp[fg + 8], v2 = rowp[fg + 16], v3 = rowp[fg + 24];

    if (isX) {
      const float4* yrp = (const float4*)(y + (size_t)row0 * DD + rloc * DD);
      float4 w0 = yrp[fg], w1 = yrp[fg + 8], w2 = yrp[fg + 16], w3 = yrp[fg + 24];
      float d = v0.x*w0.x + v0.y*w0.y + v0.z*w0.z + v0.w*w0.w
              + v1.x*w1.x + v1.y*w1.y + v1.z*w1.z + v1.w*w1.w
              + v2.x*w2.x + v2.y*w2.y + v2.z*w2.z + v2.w*w2.w
              + v3.x*w3.x + v3.y*w3.y + v3.z*w3.z + v3.w*w3.w;
      d += __shfl_down(d, 4, 8);
      d += __shfl_down(d, 2, 8);
      d += __shfl_down(d, 1, 8);
      if (fg == 0) { s1 += (double)d; s2 += (double)d * (double)d; }
    }

    {
      float vals[16] = {v0.x, v0.y, v0.z, v0.w, v1.x, v1.y, v1.z, v1.w,
                        v2.x, v2.y, v2.z, v2.w, v3.x, v3.y, v3.z, v3.w};
#pragma unroll
      for (int j = 0; j < 4; ++j)
#pragma unroll
        for (int cc = 0; cc < 4; ++cc) {
          const int m = ((fg + (j << 3)) << 2) + cc;
          const float vv = vals[j * 4 + cc];
          const unsigned int b = __float_as_uint(vv);
          const unsigned short hb = (unsigned short)(b >> 16);
          const float hf = __uint_as_float(b & 0xffff0000u);
          const float lf = vv - hf;
          const unsigned short lb = (unsigned short)(__float_as_uint(lf) >> 16);
          sh_hi[m * SR + rloc] = hb;
          sh_lo[m * SR + rloc] = lb;
        }
    }
    __syncthreads();

#pragma unroll
    for (int j = 0; j < 5; ++j) {
      if (j < cnt) {
        const int ar0 = (tr_[j] * 16 + (lane & 15)) * SR;
        const int br0 = (tc_[j] * 16 + (lane & 15)) * SR;
#pragma unroll
        for (int kb = 0; kb < 64; kb += 32) {
          const int ko = kb + ((lane >> 4) << 3);
          const s16x8 ahi = *(const s16x8*)&sh_hi[ar0 + ko];
          const s16x8 alo = *(const s16x8*)&sh_lo[ar0 + ko];
          const s16x8 bhi = *(const s16x8*)&sh_hi[br0 + ko];
          const s16x8 blo = *(const s16x8*)&sh_lo[br0 + ko];
          acc[j] = __builtin_amdgcn_mfma_f32_16x16x32_bf16(ahi, bhi, acc[j], 0, 0, 0);
          acc[j] = __builtin_amdgcn_mfma_f32_16x16x32_bf16(ahi, blo, acc[j], 0, 0, 0);
          acc[j] = __builtin_amdgcn_mfma_f32_16x16x32_bf16(alo, bhi, acc[j], 0, 0, 0);
        }
      }
    }

    // packed upper-triangle store: tile t -> f32x4 slots [t*64, t*64+64)
    f32x4* __restrict__ dst4 = (f32x4*)(isX ? apart : bpart) + (size_t)p * (NT * 64);
#pragma unroll
    for (int j = 0; j < 5; ++j)
      if (j < cnt) dst4[(start + j) * 64 + lane] = acc[j];

    if (isX) {
      s1 += __shfl_down(s1, 32, 64); s2 += __shfl_down(s2, 32, 64);
      s1 += __shfl_down(s1, 16, 64); s2 += __shfl_down(s2, 16, 64);
      s1 += __shfl_down(s1, 8, 64);  s2 += __shfl_down(s2, 8, 64);
      if (lane == 0) { wred[wave][0] = s1; wred[wave][1] = s2; }
      __syncthreads();
      if (tid == 0) {
        double t1 = 0.0, t2 = 0.0;
#pragma unroll
        for (int g = 0; g < 8; ++g) { t1 += wred[g][0]; t2 += wred[g][1]; }
        ds1[p] = t1;
        ds2[p] = t2;
      }
    }
  }

  __threadfence();
  cg::this_grid().sync();
  __threadfence();

  // ================= phase 2: dot (blocks 0..143) =================
  if (blk < DOTB) {
    const int s = tid & 15;          // f4 slot within this block's 16
    const int pg = tid >> 4;         // p-group 0..31
    const f32x4* a4 = (const f32x4*)apart;
    const f32x4* b4 = (const f32x4*)bpart;
    const int base = blk * 16 + s;   // f4 index within a partial [0,2304)

    f32x4 sa = {0.f, 0.f, 0.f, 0.f}, sb = {0.f, 0.f, 0.f, 0.f};
#pragma unroll
    for (int i = 0; i < 4; ++i) {
      const int p = pg + (i << 5);
      sa += a4[(size_t)p * (NT * 64) + base];
      sb += b4[(size_t)p * (NT * 64) + base];
    }

    f32x4* sA = (f32x4*)smem;        // [32][16], reuses gram LDS (16 KB x2)
    f32x4* sB = sA + 512;
    sA[pg * 16 + s] = sa;
    sB[pg * 16 + s] = sb;
    __syncthreads();

    if (tid < 16) {
      f32x4 ta = sA[tid], tb = sB[tid];
#pragma unroll
      for (int g = 1; g < 32; ++g) { ta += sA[g * 16 + tid]; tb += sB[g * 16 + tid]; }
      const int tile = (blk * 16 + tid) >> 6;   // 64 f4 per sub-tile
      const double w = ((0xA44208101ULL >> tile) & 1) ? 1.0 : 2.0;
      double pr = w * ((double)ta[0] * (double)tb[0]
                     + (double)ta[1] * (double)tb[1]
                     + (double)ta[2] * (double)tb[2]
                     + (double)ta[3] * (double)tb[3]);
      pr += __shfl_down(pr, 8, 16);
      pr += __shfl_down(pr, 4, 16);
      pr += __shfl_down(pr, 2, 16);
      pr += __shfl_down(pr, 1, 16);
      if (tid == 0) prod[blk] = pr;
    }
  }

  __threadfence();
  cg::this_grid().sync();
  __threadfence();

  // ================= phase 3: finish (block 0) =================
  if (blk == 0) {
    double S  = (tid < DOTB) ? prod[tid] : 0.0;   // 144 entries
    double t1 = (tid < PP) ? ds1[tid] : 0.0;      // 128 entries
    double t2 = (tid < PP) ? ds2[tid] : 0.0;
#pragma unroll
    for (int off = 32; off > 0; off >>= 1) {
      S  += __shfl_down(S, off, 64);
      t1 += __shfl_down(t1, off, 64);
      t2 += __shfl_down(t2, off, 64);
    }
    __syncthreads();   // LDS reuse barrier (wred untouched since phase 1 X-diag)
    if (lane == 0) { wred[wave][0] = S; wred[wave][1] = t1; wred[wave][2] = t2; }
    __syncthreads();
    if (tid == 0) {
      double Sf = 0.0, d1 = 0.0, d2 = 0.0;
#pragma unroll
      for (int g = 0; g < 8; ++g) { Sf += wred[g][0]; d1 += wred[g][1]; d2 += wred[g][2]; }
      double loss = (Sf - d2) / ((double)N * (double)(N - 1)) - (2.0 / N) * d1;
      out[0] = (float)loss;
    }
  }
}

extern "C" void kernel_launch(void* const* d_in, const int* in_sizes, int n_in,
                              void* d_out, int out_size, void* d_ws, size_t ws_size,
                              hipStream_t stream) {
  const float* x = (const float*)d_in[0];
  const float* y = (const float*)d_in[1];
  float* out = (float*)d_out;
  int N = in_sizes[0] / DD;  // 8192

  char* w = (char*)d_ws;
  float* apart = (float*)w;                              w += (size_t)PP * NT * 256 * 4;
  float* bpart = (float*)w;                              w += (size_t)PP * NT * 256 * 4;
  double* ds1  = (double*)w;                             w += PP * 8;
  double* ds2  = (double*)w;                             w += PP * 8;
  double* prod = (double*)w;

  void* args[] = {(void*)&x, (void*)&y, (void*)&apart, (void*)&bpart,
                  (void*)&ds1, (void*)&ds2, (void*)&prod, (void*)&out, (void*)&N};
  hipLaunchCooperativeKernel((const void*)fused_kernel, dim3(NB), dim3(512),
                             args, 0, stream);
}

// Round 4
// 68.817 us; speedup vs baseline: 4.2464x; 4.2464x over previous
//
#include <hip/hip_runtime.h>

#define DD 128   // feature dim
#define SR 72    // LDS row stride in bf16 units (64 + 8 pad, bank-spread)
#define PP 128   // partial tiles per matrix
#define NB (2*PP)
#define NT 36    // upper-triangle 16x16 sub-tiles per partial (8*9/2)
#define DOTB 144 // dot-phase blocks = NT*64/16

typedef float f32x4 __attribute__((ext_vector_type(4)));
typedef short s16x8 __attribute__((ext_vector_type(8)));

// ---------------------------------------------------------------------------
// R14: back to stream-ordered dispatches (R13 post-mortem: cg::grid.sync costs
// ~100 us each on 256 blocks / 8 XCDs — kernel boundaries are ~2-3 us).
// Structural cut instead: loss is LINEAR in (S, d1, d2), so the finish kernel
// is replaced by 145 one-shot device-scope atomicAdd(float) contributions to
// out[0] from dispatch 2. out[0] is zero-initialized by a plain store from
// gram block 0 (kernel boundary orders it before dot's atomics — same
// guarantee the partial tiles rely on). NO spin/ticket, NO grid sync.
//   dispatch 1 (gram, 256 blocks): symmetric Gram partials via hi/lo-split
//     bf16 MFMA, 36 packed upper-triangle 16x16 sub-tiles; X-blocks fold
//     diag sums ds1/ds2 (plain stores); block 0 stores out[0]=0.
//   dispatch 2 (dotfin, 145 blocks): blocks 0..143 sum partials elementwise,
//     weighted Frobenius dot (off-diag tiles x2), atomicAdd pr/(N(N-1));
//     block 144 reduces ds1/ds2, atomicAdd (-d2/(N(N-1)) - 2 d1/N).
// ---------------------------------------------------------------------------
__global__ __launch_bounds__(512)
void gram_kernel(const float* __restrict__ x, const float* __restrict__ y,
                 float* __restrict__ apart, float* __restrict__ bpart,
                 double* __restrict__ ds1, double* __restrict__ ds2,
                 float* __restrict__ out, int N)
{
  const int blk = blockIdx.x;
  const bool isX = blk < PP;
  const int p = isX ? blk : blk - PP;
  const float* __restrict__ src = isX ? x : y;
  const int slab = N / PP;       // 64
  const int row0 = p * slab;

  __shared__ __align__(16) unsigned short sh_hi[DD * SR];  // 18.4 KB
  __shared__ __align__(16) unsigned short sh_lo[DD * SR];  // 18.4 KB
  __shared__ double wred[8][2];

  const int tid = threadIdx.x;
  const int wave = tid >> 6, lane = tid & 63;
  const int rloc = tid >> 3;     // row within 64-row chunk
  const int fg = tid & 7;        // float4 group within row

  if (blk == 0 && tid == 0) out[0] = 0.0f;   // zero-init for dispatch-2 atomics

  // static upper-triangle tile list: wave w owns packed tiles
  // [start, start+cnt), 4 or 5 each.
  const int start = (9 * wave) >> 1;          // {0,4,9,13,18,22,27,31}
  const int cnt = 4 + (wave & 1);             // {4,5,4,5,4,5,4,5}
  int tr_[5], tc_[5];
#pragma unroll
  for (int j = 0; j < 5; ++j) {
    const int tile = start + j;
    int r = 0;
#pragma unroll
    for (int q = 1; q < 8; ++q) r += (tile >= ((q * (17 - q)) >> 1)) ? 1 : 0;
    tr_[j] = r;
    tc_[j] = tile - ((r * (17 - r)) >> 1) + r;  // c = r + (tile - rowstart(r))
  }

  f32x4 acc[5];
#pragma unroll
  for (int t = 0; t < 5; ++t)
#pragma unroll
    for (int k = 0; k < 4; ++k) acc[t][k] = 0.f;

  double s1 = 0.0, s2 = 0.0;

  {
    const float* cb = src + (size_t)row0 * DD;
    const float4* rowp = (const float4*)(cb + rloc * DD);
    float4 v0 = rowp[fg], v1 = rowp[fg + 8], v2 = rowp[fg + 16], v3 = rowp[fg + 24];

    if (isX) {
      const float4* yrp = (const float4*)(y + (size_t)row0 * DD + rloc * DD);
      float4 w0 = yrp[fg], w1 = yrp[fg + 8], w2 = yrp[fg + 16], w3 = yrp[fg + 24];
      float d = v0.x*w0.x + v0.y*w0.y + v0.z*w0.z + v0.w*w0.w
              + v1.x*w1.x + v1.y*w1.y + v1.z*w1.z + v1.w*w1.w
              + v2.x*w2.x + v2.y*w2.y + v2.z*w2.z + v2.w*w2.w
              + v3.x*w3.x + v3.y*w3.y + v3.z*w3.z + v3.w*w3.w;
      d += __shfl_down(d, 4, 8);
      d += __shfl_down(d, 2, 8);
      d += __shfl_down(d, 1, 8);
      if (fg == 0) { s1 += (double)d; s2 += (double)d * (double)d; }
    }

    {
      float vals[16] = {v0.x, v0.y, v0.z, v0.w, v1.x, v1.y, v1.z, v1.w,
                        v2.x, v2.y, v2.z, v2.w, v3.x, v3.y, v3.z, v3.w};
#pragma unroll
      for (int j = 0; j < 4; ++j)
#pragma unroll
        for (int cc = 0; cc < 4; ++cc) {
          const int m = ((fg + (j << 3)) << 2) + cc;
          const float vv = vals[j * 4 + cc];
          const unsigned int b = __float_as_uint(vv);
          const unsigned short hb = (unsigned short)(b >> 16);
          const float hf = __uint_as_float(b & 0xffff0000u);
          const float lf = vv - hf;
          const unsigned short lb = (unsigned short)(__float_as_uint(lf) >> 16);
          sh_hi[m * SR + rloc] = hb;
          sh_lo[m * SR + rloc] = lb;
        }
    }
    __syncthreads();

#pragma unroll
    for (int j = 0; j < 5; ++j) {
      if (j < cnt) {
        const int ar0 = (tr_[j] * 16 + (lane & 15)) * SR;
        const int br0 = (tc_[j] * 16 + (lane & 15)) * SR;
#pragma unroll
        for (int kb = 0; kb < 64; kb += 32) {
          const int ko = kb + ((lane >> 4) << 3);
          const s16x8 ahi = *(const s16x8*)&sh_hi[ar0 + ko];
          const s16x8 alo = *(const s16x8*)&sh_lo[ar0 + ko];
          const s16x8 bhi = *(const s16x8*)&sh_hi[br0 + ko];
          const s16x8 blo = *(const s16x8*)&sh_lo[br0 + ko];
          acc[j] = __builtin_amdgcn_mfma_f32_16x16x32_bf16(ahi, bhi, acc[j], 0, 0, 0);
          acc[j] = __builtin_amdgcn_mfma_f32_16x16x32_bf16(ahi, blo, acc[j], 0, 0, 0);
          acc[j] = __builtin_amdgcn_mfma_f32_16x16x32_bf16(alo, bhi, acc[j], 0, 0, 0);
        }
      }
    }
  }

  // packed upper-triangle store: tile t -> f32x4 slots [t*64, t*64+64)
  f32x4* __restrict__ dst4 = (f32x4*)(isX ? apart : bpart) + (size_t)p * (NT * 64);
#pragma unroll
  for (int j = 0; j < 5; ++j)
    if (j < cnt) dst4[(start + j) * 64 + lane] = acc[j];

  if (isX) {
    // diag partials live on lanes 0,8,...,56 of each wave
    s1 += __shfl_down(s1, 32, 64); s2 += __shfl_down(s2, 32, 64);
    s1 += __shfl_down(s1, 16, 64); s2 += __shfl_down(s2, 16, 64);
    s1 += __shfl_down(s1, 8, 64);  s2 += __shfl_down(s2, 8, 64);
    if (lane == 0) { wred[wave][0] = s1; wred[wave][1] = s2; }
    __syncthreads();
    if (tid == 0) {
      double t1 = 0.0, t2 = 0.0;
#pragma unroll
      for (int g = 0; g < 8; ++g) { t1 += wred[g][0]; t2 += wred[g][1]; }
      ds1[p] = t1;   // plain stores, no init required
      ds2[p] = t2;
    }
  }
}

// ---------------------------------------------------------------------------
// Dispatch 2: dot + finish. Blocks 0..143: elementwise sum-over-p of the
// packed 36-tile partials, weighted Gx*Gy dot (off-diag tiles x2), one
// atomicAdd(float) of pr/(N(N-1)) to out[0]. Block 144: reduce the 128
// ds1/ds2 doubles, one atomicAdd of (-d2/(N(N-1)) - 2/N * d1).
// 145 one-shot atomics total to a single address — no ordering assumptions.
// ---------------------------------------------------------------------------
__global__ __launch_bounds__(256)
void dotfin_kernel(const float* __restrict__ apart, const float* __restrict__ bpart,
                   const double* __restrict__ ds1, const double* __restrict__ ds2,
                   float* __restrict__ out, int N)
{
  __shared__ f32x4 sA[16][16], sB[16][16];   // dot-branch LDS (16 KB)
  __shared__ double red[4][2];               // diag-branch LDS

  const int blk = blockIdx.x;
  const int tid = threadIdx.x;
  const double invNN1 = 1.0 / ((double)N * (double)(N - 1));

  if (blk < DOTB) {
    const int s = tid & 15;          // f4 slot within this block's 16
    const int pg = tid >> 4;         // p-group 0..15
    const f32x4* a4 = (const f32x4*)apart;
    const f32x4* b4 = (const f32x4*)bpart;
    const int base = blk * 16 + s;   // f4 index within a partial [0,2304)

    f32x4 sa = {0.f, 0.f, 0.f, 0.f}, sb = {0.f, 0.f, 0.f, 0.f};
#pragma unroll
    for (int i = 0; i < 8; ++i) {
      const int p = pg + (i << 4);
      sa += a4[(size_t)p * (NT * 64) + base];
      sb += b4[(size_t)p * (NT * 64) + base];
    }

    sA[pg][s] = sa;
    sB[pg][s] = sb;
    __syncthreads();

    if (tid < 16) {
      f32x4 ta = sA[0][tid], tb = sB[0][tid];
#pragma unroll
      for (int g = 1; g < 16; ++g) { ta += sA[g][tid]; tb += sB[g][tid]; }
      const int tile = (blk * 16 + tid) >> 6;   // 64 f4 per sub-tile
      const double w = ((0xA44208101ULL >> tile) & 1) ? 1.0 : 2.0;
      double pr = w * ((double)ta[0] * (double)tb[0]
                     + (double)ta[1] * (double)tb[1]
                     + (double)ta[2] * (double)tb[2]
                     + (double)ta[3] * (double)tb[3]);
      pr += __shfl_down(pr, 8, 16);
      pr += __shfl_down(pr, 4, 16);
      pr += __shfl_down(pr, 2, 16);
      pr += __shfl_down(pr, 1, 16);
      if (tid == 0) atomicAdd(out, (float)(pr * invNN1));
    }
  } else {
    // block 144: diag-term combine
    const int wv = tid >> 6, lane = tid & 63;
    double t1 = (tid < PP) ? ds1[tid] : 0.0;
    double t2 = (tid < PP) ? ds2[tid] : 0.0;
#pragma unroll
    for (int off = 32; off > 0; off >>= 1) {
      t1 += __shfl_down(t1, off, 64);
      t2 += __shfl_down(t2, off, 64);
    }
    if (lane == 0) { red[wv][0] = t1; red[wv][1] = t2; }
    __syncthreads();
    if (tid == 0) {
      double d1 = red[0][0] + red[1][0] + red[2][0] + red[3][0];
      double d2 = red[0][1] + red[1][1] + red[2][1] + red[3][1];
      atomicAdd(out, (float)(-d2 * invNN1 - (2.0 / N) * d1));
    }
  }
}

extern "C" void kernel_launch(void* const* d_in, const int* in_sizes, int n_in,
                              void* d_out, int out_size, void* d_ws, size_t ws_size,
                              hipStream_t stream) {
  const float* x = (const float*)d_in[0];
  const float* y = (const float*)d_in[1];
  float* out = (float*)d_out;
  const int N = in_sizes[0] / DD;  // 8192

  char* w = (char*)d_ws;
  float* apart = (float*)w;                              w += (size_t)PP * NT * 256 * 4;
  float* bpart = (float*)w;                              w += (size_t)PP * NT * 256 * 4;
  double* ds1  = (double*)w;                             w += PP * 8;
  double* ds2  = (double*)w;                             w += PP * 8;

  gram_kernel<<<NB, 512, 0, stream>>>(x, y, apart, bpart, ds1, ds2, out, N);
  dotfin_kernel<<<DOTB + 1, 256, 0, stream>>>(apart, bpart, ds1, ds2, out, N);
}